// Round 9
// baseline (498.459 us; speedup 1.0000x reference)
//
#include <hip/hip_runtime.h>
#include <hip/hip_bf16.h>

#define T_TOTAL 262144
#define B_SEG   4096

typedef __attribute__((ext_vector_type(8))) short short8;
typedef __attribute__((ext_vector_type(4))) float f32x4;

__device__ __forceinline__ short f2bf(float x) {
    __hip_bfloat16 h = __float2bfloat16(x);
    return *reinterpret_cast<short*>(&h);
}
__device__ __forceinline__ float bf2f(short s) {
    unsigned u = ((unsigned)(unsigned short)s) << 16;
    return __uint_as_float(u);
}

// ---------------------------------------------------------------------------
// prep_all: merged independent prep work (one launch).
//   blocks [0,40):     transpose W1/W2/W3v -> bf16 [N][K]
//   blocks [40,42):    vec (bz / wc / c0)
//   blocks [42,554):   prep_wqz  (Wqz = Wq . W3k^T, 16x16 tiles)
//   blocks [554,682):  cvec (cbuf[s] = ctx[s].wc + c0)
//   blocks [682,1706): seg_starts (starts[s] = first t with seg[t]==s)
// ---------------------------------------------------------------------------
__global__ __launch_bounds__(256) void prep_all(
    const float* __restrict__ W1, const float* __restrict__ W2,
    const float* __restrict__ W3, const float* __restrict__ Wq,
    const float* __restrict__ bq, const float* __restrict__ b3,
    const float* __restrict__ ctx, const int* __restrict__ seg,
    short* __restrict__ W1T, short* __restrict__ W2T, short* __restrict__ W3vT,
    float* __restrict__ bz, float* __restrict__ wc, float* __restrict__ c0,
    float* __restrict__ Wqz, float* __restrict__ cbuf,
    int* __restrict__ starts) {
    __shared__ __align__(16) char smem[33280];
    const int b = blockIdx.x, tid = threadIdx.x;

    if (b < 40) {
        float (*t)[68] = reinterpret_cast<float(*)[68]>(smem);
        const float* src; short* dst;
        int k0, n0_src, n0_dst, sstride, dstride;
        if (b < 8) {
            int kt = b >> 2, nt = b & 3;
            src = W1; dst = W1T; sstride = 256; dstride = 128;
            k0 = kt * 64; n0_src = nt * 64; n0_dst = nt * 64;
        } else if (b < 24) {
            int id = b - 8, kt = id >> 2, nt = id & 3;
            src = W2; dst = W2T; sstride = 256; dstride = 256;
            k0 = kt * 64; n0_src = nt * 64; n0_dst = nt * 64;
        } else {
            int id = b - 24, kt = id >> 2, nt = id & 3;
            src = W3; dst = W3vT; sstride = 512; dstride = 256;
            k0 = kt * 64; n0_src = 256 + nt * 64; n0_dst = nt * 64;
        }
        {
            int r = tid >> 4, c4 = (tid & 15) * 4;
#pragma unroll
            for (int p = 0; p < 4; p++) {
                int k = p * 16 + r;
                float4 v = *reinterpret_cast<const float4*>(
                    &src[(size_t)(k0 + k) * sstride + n0_src + c4]);
                *reinterpret_cast<float4*>(&t[k][c4]) = v;
            }
        }
        __syncthreads();
        {
            int n = tid >> 2, kq = tid & 3;
            short8 s0, s1;
#pragma unroll
            for (int i = 0; i < 8; i++) s0[i] = f2bf(t[kq * 16 + i][n]);
#pragma unroll
            for (int i = 0; i < 8; i++) s1[i] = f2bf(t[kq * 16 + 8 + i][n]);
            short* o = &dst[(size_t)(n0_dst + n) * dstride + k0 + kq * 16];
            *reinterpret_cast<short8*>(o) = s0;
            *reinterpret_cast<short8*>(o + 8) = s1;
        }
    } else if (b < 42) {
        if (b == 40) {
            float s = 0.f;
            for (int n = 0; n < 256; n += 4) {
                float4 a = *reinterpret_cast<const float4*>(&W3[(size_t)tid * 512 + n]);
                float4 v = *reinterpret_cast<const float4*>(&bq[n]);
                s += a.x * v.x + a.y * v.y + a.z * v.z + a.w * v.w;
            }
            bz[tid] = s;
        } else {
#pragma unroll
            for (int h = 0; h < 2; h++) {
                int c = h * 256 + tid;
                float s = 0.f;
                for (int n = 0; n < 256; n += 4) {
                    float4 a = *reinterpret_cast<const float4*>(&Wq[(size_t)c * 256 + n]);
                    float4 v = *reinterpret_cast<const float4*>(&b3[n]);
                    s += a.x * v.x + a.y * v.y + a.z * v.z + a.w * v.w;
                }
                wc[c] = s;
            }
            if (tid == 0) {
                float s = 0.f;
                for (int n = 0; n < 256; n++) s += bq[n] * b3[n];
                c0[0] = s;
            }
        }
    } else if (b < 554) {
        float (*wq)[260] = reinterpret_cast<float(*)[260]>(smem);
        float (*w3)[260] = reinterpret_cast<float(*)[260]>(smem + 16640);
        const int id = b - 42;
        const int c0r = (id >> 4) * 16, j0 = (id & 15) * 16;
        {
            int r = tid >> 4, nq = tid & 15;
#pragma unroll
            for (int p = 0; p < 4; p++) {
                int col = nq * 4 + p * 64;
                *reinterpret_cast<float4*>(&wq[r][col]) =
                    *reinterpret_cast<const float4*>(&Wq[(size_t)(c0r + r) * 256 + col]);
                *reinterpret_cast<float4*>(&w3[r][col]) =
                    *reinterpret_cast<const float4*>(&W3[(size_t)(j0 + r) * 512 + col]);
            }
        }
        __syncthreads();
        const int ci = tid >> 4, ji = tid & 15;
        float s = 0.f;
        for (int n = 0; n < 256; n += 4) {
            float4 a = *reinterpret_cast<const float4*>(&wq[ci][n]);
            float4 v = *reinterpret_cast<const float4*>(&w3[ji][n]);
            s += a.x * v.x + a.y * v.y + a.z * v.z + a.w * v.w;
        }
        Wqz[(size_t)(c0r + ci) * 256 + j0 + ji] = s;
    } else if (b < 682) {
        const int id = b - 554;
        const int row = id * 32 + (tid >> 3);
        const int l = tid & 7;
        float s = 0.f;
        for (int i = 0; i < 64; i += 4) {
            float4 a = *reinterpret_cast<const float4*>(&ctx[(size_t)row * 512 + l * 64 + i]);
            float4 v = *reinterpret_cast<const float4*>(&wc[l * 64 + i]);
            s += a.x * v.x + a.y * v.y + a.z * v.z + a.w * v.w;
        }
        s += __shfl_xor(s, 1); s += __shfl_xor(s, 2); s += __shfl_xor(s, 4);
        if (l == 0) cbuf[row] = s + c0[0];
    } else {
        int t = (b - 682) * 256 + tid;
        if (t < T_TOTAL) {
            int s = seg[t];
            if (t == 0) {
                for (int q = 0; q <= s; q++) starts[q] = 0;
            } else {
                int p = seg[t - 1];
                for (int q = p + 1; q <= s; q++) starts[q] = t;
            }
        }
    }
}

// ---------------------------------------------------------------------------
// zq_kernel: ZQ = context @ Wqz + bz  (fp32 [4096][256]); BM=32 tiles,
// grid (128,4) = 512 blocks = 2 blocks/CU.
// ---------------------------------------------------------------------------
__global__ __launch_bounds__(256) void zq_kernel(
    const float* __restrict__ ctx, const float* __restrict__ Wqz,
    const float* __restrict__ bz, float* __restrict__ zq) {
    __shared__ float As[2][16][44];
    const int tid = threadIdx.x;
    const int tm = tid & 7, tn = tid >> 3;
    const int row0 = blockIdx.x * 32, col0 = blockIdx.y * 64;
    const int lr = tid >> 3, lk = tid & 7;

    float acc[4][2];
#pragma unroll
    for (int i = 0; i < 4; i++) { acc[i][0] = 0.f; acc[i][1] = 0.f; }

    float2 av = *reinterpret_cast<const float2*>(&ctx[(size_t)(row0 + lr) * 512 + lk * 2]);
    for (int c = 0; c < 32; c++) {
        int cur = c & 1;
        As[cur][lk * 2 + 0][lr] = av.x;
        As[cur][lk * 2 + 1][lr] = av.y;
        __syncthreads();
        if (c < 31)
            av = *reinterpret_cast<const float2*>(
                &ctx[(size_t)(row0 + lr) * 512 + (c + 1) * 16 + lk * 2]);
#pragma unroll
        for (int k = 0; k < 16; k++) {
            float4 a = *reinterpret_cast<const float4*>(&As[cur][k][tm * 4]);
            float2 b = *reinterpret_cast<const float2*>(
                &Wqz[(size_t)(c * 16 + k) * 256 + col0 + tn * 2]);
            acc[0][0] += a.x * b.x; acc[0][1] += a.x * b.y;
            acc[1][0] += a.y * b.x; acc[1][1] += a.y * b.y;
            acc[2][0] += a.z * b.x; acc[2][1] += a.z * b.y;
            acc[3][0] += a.w * b.x; acc[3][1] += a.w * b.y;
        }
    }
    float2 bv = *reinterpret_cast<const float2*>(&bz[col0 + tn * 2]);
#pragma unroll
    for (int i = 0; i < 4; i++) {
        float2 o = {acc[i][0] + bv.x, acc[i][1] + bv.y};
        *reinterpret_cast<float2*>(
            &zq[(size_t)(row0 + tm * 4 + i) * 256 + col0 + tn * 2]) = o;
    }
}

// ---------------------------------------------------------------------------
// mlp_kernel: M=128 tile, 8 waves (2M x 4N), wave = 64x64 output, acc 64 AGPR.
// __launch_bounds__(512,2) -> 256-reg budget/wave; demand = acc 64 + W-dbuf
// 32 + A-dbuf 32 + addr ~20 = ~150 (headroom ~100; tripwire: WRITE_SIZE >
// 150 MB = spill). LDS 66KB -> 2 blocks/CU = 16 waves/CU. This keeps R6's
// per-tile-overhead amortization (confirmed +) and removes R6's spill.
// v stored directly from accumulators (no LDS round-trip, one less barrier).
// Swizzle (all K): elem(m,k) at m*K + ((k>>3)^(m&15))*8 + (k&7).
// MFMA operand swap: D = W_frag x act_frag -> lane holds 4 consecutive n.
// ---------------------------------------------------------------------------
template <int K>
__device__ __forceinline__ void run_layer(
    const short* __restrict__ act, const short* __restrict__ Wt,
    int mbase, int nbase, int l16, int quad, f32x4 acc[4][4]) {
    constexpr int KK = K / 32;
    const f32x4 zero = {0.f, 0.f, 0.f, 0.f};
#pragma unroll
    for (int i = 0; i < 4; i++)
#pragma unroll
        for (int j = 0; j < 4; j++) acc[i][j] = zero;

    int woff[4];
#pragma unroll
    for (int ns = 0; ns < 4; ns++)
        woff[ns] = ((nbase + ns * 16 + l16) * K + quad * 8) * 2;
    const int abase = (mbase + l16) * K * 2;
    const char* actc = reinterpret_cast<const char*>(act);
    const char* wtc  = reinterpret_cast<const char*>(Wt);

    short8 wbuf[2][4];
    short8 areg[2][4];

    auto loadA = [&](int kk, int slot) {
        const int sg = (((kk * 4 + quad) ^ l16) * 16);
#pragma unroll
        for (int ms = 0; ms < 4; ms++)
            areg[slot][ms] = *reinterpret_cast<const short8*>(
                actc + abase + ms * 16 * K * 2 + sg);
    };
    auto loadW = [&](int kk, int slot) {
#pragma unroll
        for (int ns = 0; ns < 4; ns++)
            wbuf[slot][ns] = *reinterpret_cast<const short8*>(
                wtc + woff[ns] + kk * 64);
    };

    loadW(0, 0); loadA(0, 0);
    loadW(1, 1); loadA(1, 1);
#pragma unroll
    for (int kk = 0; kk < KK; kk++) {
        const int cur = kk & 1;
#pragma unroll
        for (int ms = 0; ms < 4; ms++)
#pragma unroll
            for (int ns = 0; ns < 4; ns++)
                acc[ms][ns] = __builtin_amdgcn_mfma_f32_16x16x32_bf16(
                    wbuf[cur][ns], areg[cur][ms], acc[ms][ns], 0, 0, 0);
        if (kk + 2 < KK) { loadW(kk + 2, cur); loadA(kk + 2, cur); }
    }
}

__global__ __launch_bounds__(512, 2) void mlp_kernel(
    const float* __restrict__ objects, const int* __restrict__ seg_ids,
    const short* __restrict__ W1T, const short* __restrict__ W2T,
    const short* __restrict__ W3vT,
    const float* __restrict__ b1, const float* __restrict__ b2,
    const float* __restrict__ b3,
    const float* __restrict__ zqbuf, const float* __restrict__ cbuf,
    float* __restrict__ logits_out, short* __restrict__ vout) {
    __shared__ __align__(16) short bufH[128 * 256];   // 64 KB: X -> h1 -> h2
    __shared__ float slots[4][128];

    const int tid  = threadIdx.x;
    const int wave = tid >> 6;
    const int lane = tid & 63;
    const int quad = lane >> 4;
    const int l16  = lane & 15;
    const int mbase = (wave & 1) * 64;
    const int wn    = wave >> 1;
    const int nbase = wn * 64;
    const int row0  = blockIdx.x * 128;

    // ---- stage X (fp32 -> bf16, K=128 swizzled layout in bufH[0:32KB])
    {
        const float4* op = reinterpret_cast<const float4*>(objects + (size_t)row0 * 128);
#pragma unroll
        for (int i = 0; i < 4; i++) {
            int u = tid + i * 512;           // 0..2047: m = u>>4, kg = u&15
            int m = u >> 4, kg = u & 15;
            float4 x0 = op[u * 2];
            float4 x1 = op[u * 2 + 1];
            short8 s;
            s[0] = f2bf(x0.x); s[1] = f2bf(x0.y); s[2] = f2bf(x0.z); s[3] = f2bf(x0.w);
            s[4] = f2bf(x1.x); s[5] = f2bf(x1.y); s[6] = f2bf(x1.z); s[7] = f2bf(x1.w);
            *reinterpret_cast<short8*>(&bufH[m * 128 + ((kg ^ (m & 15)) * 8)]) = s;
        }
    }
    __syncthreads();

    f32x4 acc[4][4];

    auto store_act = [&](const float* __restrict__ bias) {
#pragma unroll
        for (int ns = 0; ns < 4; ns++) {
            int n0 = nbase + ns * 16 + quad * 4;
            float4 bv = *reinterpret_cast<const float4*>(&bias[n0]);
#pragma unroll
            for (int ms = 0; ms < 4; ms++) {
                int m = mbase + ms * 16 + l16;
                short4 s;
                s.x = f2bf(fmaxf(acc[ms][ns][0] + bv.x, 0.f));
                s.y = f2bf(fmaxf(acc[ms][ns][1] + bv.y, 0.f));
                s.z = f2bf(fmaxf(acc[ms][ns][2] + bv.z, 0.f));
                s.w = f2bf(fmaxf(acc[ms][ns][3] + bv.w, 0.f));
                *reinterpret_cast<short4*>(
                    &bufH[m * 256 + (((n0 >> 3) ^ (m & 15)) * 8) + (n0 & 7)]) = s;
            }
        }
    };

    // ---- layer 1: h1 = relu(X @ W1 + b1)
    run_layer<128>(bufH, W1T, mbase, nbase, l16, quad, acc);
    __syncthreads();                 // X fully consumed
    store_act(b1);
    __syncthreads();

    // ---- layer 2: h2 = relu(h1 @ W2 + b2); fold logits = h2.zq[seg]
    run_layer<256>(bufH, W2T, mbase, nbase, l16, quad, acc);
    __syncthreads();                 // h1 fully consumed
    {
        float part[4] = {0.f, 0.f, 0.f, 0.f};
        int segm[4];
#pragma unroll
        for (int ms = 0; ms < 4; ms++) segm[ms] = seg_ids[row0 + mbase + ms * 16 + l16];
#pragma unroll
        for (int ns = 0; ns < 4; ns++) {
            int n0 = nbase + ns * 16 + quad * 4;
            float4 bv = *reinterpret_cast<const float4*>(&b2[n0]);
#pragma unroll
            for (int ms = 0; ms < 4; ms++) {
                int m = mbase + ms * 16 + l16;
                float h0 = fmaxf(acc[ms][ns][0] + bv.x, 0.f);
                float h1v = fmaxf(acc[ms][ns][1] + bv.y, 0.f);
                float h2v = fmaxf(acc[ms][ns][2] + bv.z, 0.f);
                float h3 = fmaxf(acc[ms][ns][3] + bv.w, 0.f);
                short4 s;
                s.x = f2bf(h0); s.y = f2bf(h1v); s.z = f2bf(h2v); s.w = f2bf(h3);
                *reinterpret_cast<short4*>(
                    &bufH[m * 256 + (((n0 >> 3) ^ (m & 15)) * 8) + (n0 & 7)]) = s;
                float4 zq4 = *reinterpret_cast<const float4*>(
                    &zqbuf[(size_t)segm[ms] * 256 + n0]);
                part[ms] += h0 * zq4.x + h1v * zq4.y + h2v * zq4.z + h3 * zq4.w;
            }
        }
#pragma unroll
        for (int ms = 0; ms < 4; ms++) {
            float p = part[ms];
            p += __shfl_xor(p, 16);
            p += __shfl_xor(p, 32);
            if (quad == 0) slots[wn][mbase + ms * 16 + l16] = p;
        }
    }
    __syncthreads();
    if (tid < 128) {
        int seg = seg_ids[row0 + tid];
        float s = slots[0][tid] + slots[1][tid] + slots[2][tid] + slots[3][tid] + cbuf[seg];
        logits_out[row0 + tid] = s * 0.0625f;   // / sqrt(256)
    }

    // ---- layer 3 v-half: v = h2 @ W3v + b3v; store direct from acc
    run_layer<256>(bufH, W3vT, mbase, nbase, l16, quad, acc);
#pragma unroll
    for (int ns = 0; ns < 4; ns++) {
        int n0 = nbase + ns * 16 + quad * 4;
        float4 bv = *reinterpret_cast<const float4*>(&b3[256 + n0]);
#pragma unroll
        for (int ms = 0; ms < 4; ms++) {
            int m = mbase + ms * 16 + l16;
            short4 s;
            s.x = f2bf(acc[ms][ns][0] + bv.x);
            s.y = f2bf(acc[ms][ns][1] + bv.y);
            s.z = f2bf(acc[ms][ns][2] + bv.z);
            s.w = f2bf(acc[ms][ns][3] + bv.w);
            *reinterpret_cast<short4*>(
                &vout[(size_t)(row0 + m) * 256 + n0]) = s;
        }
    }
}

// ---------------------------------------------------------------------------
// segment_kernel: per-segment softmax + weighted sum of v. One wave/segment.
// v-sum: short8/lane, 2 rows per wave-instruction, 4 pairs unrolled.
// ---------------------------------------------------------------------------
__global__ __launch_bounds__(64) void segment_kernel(
    const float* __restrict__ logits, const short* __restrict__ vbuf,
    const int* __restrict__ starts, float* __restrict__ emb,
    float* __restrict__ wout) {
    const int b = blockIdx.x;
    const int lane = threadIdx.x;
    const int start = starts[b];
    const int end = (b == B_SEG - 1) ? T_TOTAL : starts[b + 1];

    float mx = -1e30f;
    for (int t = start + lane; t < end; t += 64) mx = fmaxf(mx, logits[t]);
#pragma unroll
    for (int off = 32; off >= 1; off >>= 1) mx = fmaxf(mx, __shfl_xor(mx, off));

    float s = 0.f;
    for (int t = start + lane; t < end; t += 64) s += __expf(logits[t] - mx);
#pragma unroll
    for (int off = 32; off >= 1; off >>= 1) s += __shfl_xor(s, off);
    const float invz = 1.f / s;

    for (int t = start + lane; t < end; t += 64)
        wout[t] = __expf(logits[t] - mx) * invz;

    const int half = lane >> 5;
    const int c8 = (lane & 31) * 8;
    float a[4][8];
#pragma unroll
    for (int u = 0; u < 4; u++)
#pragma unroll
        for (int j = 0; j < 8; j++) a[u][j] = 0.f;

    int t = start;
    for (; t + 8 <= end; t += 8) {
#pragma unroll
        for (int u = 0; u < 4; u++) {
            int row = t + u * 2 + half;
            float wv = __expf(logits[row] - mx) * invz;
            short8 v8 = *reinterpret_cast<const short8*>(
                &vbuf[(size_t)row * 256 + c8]);
#pragma unroll
            for (int j = 0; j < 8; j++) a[u][j] += wv * bf2f(v8[j]);
        }
    }
    for (; t < end; t += 2) {
        int row = t + half;
        if (row < end) {
            float wv = __expf(logits[row] - mx) * invz;
            short8 v8 = *reinterpret_cast<const short8*>(
                &vbuf[(size_t)row * 256 + c8]);
#pragma unroll
            for (int j = 0; j < 8; j++) a[0][j] += wv * bf2f(v8[j]);
        }
    }
    float o[8];
#pragma unroll
    for (int j = 0; j < 8; j++) {
        o[j] = a[0][j] + a[1][j] + a[2][j] + a[3][j];
        o[j] += __shfl_xor(o[j], 32);
    }
    if (half == 0) {
        float4 o0 = {o[0], o[1], o[2], o[3]};
        float4 o1 = {o[4], o[5], o[6], o[7]};
        *reinterpret_cast<float4*>(&emb[(size_t)b * 256 + c8]) = o0;
        *reinterpret_cast<float4*>(&emb[(size_t)b * 256 + c8 + 4]) = o1;
    }
}

// ---------------------------------------------------------------------------
extern "C" void kernel_launch(void* const* d_in, const int* in_sizes, int n_in,
                              void* d_out, int out_size, void* d_ws, size_t ws_size,
                              hipStream_t stream) {
    const float* objects = (const float*)d_in[0];
    const float* context = (const float*)d_in[1];
    const int*   seg     = (const int*)d_in[2];
    const float* W1 = (const float*)d_in[3];
    const float* b1 = (const float*)d_in[4];
    const float* W2 = (const float*)d_in[5];
    const float* b2 = (const float*)d_in[6];
    const float* W3 = (const float*)d_in[7];
    const float* b3 = (const float*)d_in[8];
    const float* Wq = (const float*)d_in[9];
    const float* bq = (const float*)d_in[10];

    char* ws = (char*)d_ws;
    float* zqbuf = (float*)(ws);                        // 4 MB
    float* cbuf  = (float*)(ws + 4194304);              // 16 KB
    int*   seg_starts = (int*)(ws + 4227072);           // 16 KB
    short* W1T   = (short*)(ws + 4259840);              // 64 KB
    short* W2T   = (short*)(ws + 4325376);              // 128 KB
    short* W3vT  = (short*)(ws + 4456448);              // 128 KB
    // logits region (1 MB) doubles as scratch for Wqz/bz/wc/c0 (consumed
    // before mlp_kernel writes logits over it)
    char*  lreg   = ws + 4587520;
    float* logits = (float*)lreg;
    float* Wqz    = (float*)lreg;                       // 512 KB
    float* bz     = (float*)(lreg + 524288);            // 1 KB
    float* wc     = (float*)(lreg + 525312);            // 2 KB
    float* c0     = (float*)(lreg + 527360);            // 16 B
    short* vbuf   = (short*)(ws + 5636096);             // 128 MB

    float* emb  = (float*)d_out;
    float* wout = emb + (size_t)B_SEG * 256;

    prep_all<<<1706, 256, 0, stream>>>(W1, W2, W3, Wq, bq, b3, context, seg,
                                       W1T, W2T, W3vT, bz, wc, c0, Wqz, cbuf,
                                       seg_starts);
    zq_kernel<<<dim3(128, 4), 256, 0, stream>>>(context, Wqz, bz, zqbuf);
    mlp_kernel<<<T_TOTAL / 128, 512, 0, stream>>>(objects, seg, W1T, W2T, W3vT,
                                                  b1, b2, b3, zqbuf, cbuf,
                                                  logits, vbuf);
    segment_kernel<<<B_SEG, 64, 0, stream>>>(logits, vbuf, seg_starts, emb, wout);
}

// Round 10
// 418.803 us; speedup vs baseline: 1.1902x; 1.1902x over previous
//
#include <hip/hip_runtime.h>
#include <hip/hip_bf16.h>

#define T_TOTAL 262144
#define B_SEG   4096

typedef __attribute__((ext_vector_type(8))) short short8;
typedef __attribute__((ext_vector_type(4))) float f32x4;

__device__ __forceinline__ short f2bf(float x) {
    __hip_bfloat16 h = __float2bfloat16(x);
    return *reinterpret_cast<short*>(&h);
}
__device__ __forceinline__ float bf2f(short s) {
    unsigned u = ((unsigned)(unsigned short)s) << 16;
    return __uint_as_float(u);
}

// ---------------------------------------------------------------------------
// prep_all: merged independent prep work (one launch).
//   blocks [0,40):     transpose W1/W2/W3v -> bf16 [N][K]
//   blocks [40,42):    vec (bz / wc / c0)
//   blocks [42,554):   prep_wqz  (Wqz = Wq . W3k^T, 16x16 tiles)
//   blocks [554,682):  cvec (cbuf[s] = ctx[s].wc + c0)
//   blocks [682,1706): seg_starts (starts[s] = first t with seg[t]==s)
// ---------------------------------------------------------------------------
__global__ __launch_bounds__(256) void prep_all(
    const float* __restrict__ W1, const float* __restrict__ W2,
    const float* __restrict__ W3, const float* __restrict__ Wq,
    const float* __restrict__ bq, const float* __restrict__ b3,
    const float* __restrict__ ctx, const int* __restrict__ seg,
    short* __restrict__ W1T, short* __restrict__ W2T, short* __restrict__ W3vT,
    float* __restrict__ bz, float* __restrict__ wc, float* __restrict__ c0,
    float* __restrict__ Wqz, float* __restrict__ cbuf,
    int* __restrict__ starts) {
    __shared__ __align__(16) char smem[33280];
    const int b = blockIdx.x, tid = threadIdx.x;

    if (b < 40) {
        float (*t)[68] = reinterpret_cast<float(*)[68]>(smem);
        const float* src; short* dst;
        int k0, n0_src, n0_dst, sstride, dstride;
        if (b < 8) {
            int kt = b >> 2, nt = b & 3;
            src = W1; dst = W1T; sstride = 256; dstride = 128;
            k0 = kt * 64; n0_src = nt * 64; n0_dst = nt * 64;
        } else if (b < 24) {
            int id = b - 8, kt = id >> 2, nt = id & 3;
            src = W2; dst = W2T; sstride = 256; dstride = 256;
            k0 = kt * 64; n0_src = nt * 64; n0_dst = nt * 64;
        } else {
            int id = b - 24, kt = id >> 2, nt = id & 3;
            src = W3; dst = W3vT; sstride = 512; dstride = 256;
            k0 = kt * 64; n0_src = 256 + nt * 64; n0_dst = nt * 64;
        }
        {
            int r = tid >> 4, c4 = (tid & 15) * 4;
#pragma unroll
            for (int p = 0; p < 4; p++) {
                int k = p * 16 + r;
                float4 v = *reinterpret_cast<const float4*>(
                    &src[(size_t)(k0 + k) * sstride + n0_src + c4]);
                *reinterpret_cast<float4*>(&t[k][c4]) = v;
            }
        }
        __syncthreads();
        {
            int n = tid >> 2, kq = tid & 3;
            short8 s0, s1;
#pragma unroll
            for (int i = 0; i < 8; i++) s0[i] = f2bf(t[kq * 16 + i][n]);
#pragma unroll
            for (int i = 0; i < 8; i++) s1[i] = f2bf(t[kq * 16 + 8 + i][n]);
            short* o = &dst[(size_t)(n0_dst + n) * dstride + k0 + kq * 16];
            *reinterpret_cast<short8*>(o) = s0;
            *reinterpret_cast<short8*>(o + 8) = s1;
        }
    } else if (b < 42) {
        if (b == 40) {
            float s = 0.f;
            for (int n = 0; n < 256; n += 4) {
                float4 a = *reinterpret_cast<const float4*>(&W3[(size_t)tid * 512 + n]);
                float4 v = *reinterpret_cast<const float4*>(&bq[n]);
                s += a.x * v.x + a.y * v.y + a.z * v.z + a.w * v.w;
            }
            bz[tid] = s;
        } else {
#pragma unroll
            for (int h = 0; h < 2; h++) {
                int c = h * 256 + tid;
                float s = 0.f;
                for (int n = 0; n < 256; n += 4) {
                    float4 a = *reinterpret_cast<const float4*>(&Wq[(size_t)c * 256 + n]);
                    float4 v = *reinterpret_cast<const float4*>(&b3[n]);
                    s += a.x * v.x + a.y * v.y + a.z * v.z + a.w * v.w;
                }
                wc[c] = s;
            }
            if (tid == 0) {
                float s = 0.f;
                for (int n = 0; n < 256; n++) s += bq[n] * b3[n];
                c0[0] = s;
            }
        }
    } else if (b < 554) {
        float (*wq)[260] = reinterpret_cast<float(*)[260]>(smem);
        float (*w3)[260] = reinterpret_cast<float(*)[260]>(smem + 16640);
        const int id = b - 42;
        const int c0r = (id >> 4) * 16, j0 = (id & 15) * 16;
        {
            int r = tid >> 4, nq = tid & 15;
#pragma unroll
            for (int p = 0; p < 4; p++) {
                int col = nq * 4 + p * 64;
                *reinterpret_cast<float4*>(&wq[r][col]) =
                    *reinterpret_cast<const float4*>(&Wq[(size_t)(c0r + r) * 256 + col]);
                *reinterpret_cast<float4*>(&w3[r][col]) =
                    *reinterpret_cast<const float4*>(&W3[(size_t)(j0 + r) * 512 + col]);
            }
        }
        __syncthreads();
        const int ci = tid >> 4, ji = tid & 15;
        float s = 0.f;
        for (int n = 0; n < 256; n += 4) {
            float4 a = *reinterpret_cast<const float4*>(&wq[ci][n]);
            float4 v = *reinterpret_cast<const float4*>(&w3[ji][n]);
            s += a.x * v.x + a.y * v.y + a.z * v.z + a.w * v.w;
        }
        Wqz[(size_t)(c0r + ci) * 256 + j0 + ji] = s;
    } else if (b < 682) {
        const int id = b - 554;
        const int row = id * 32 + (tid >> 3);
        const int l = tid & 7;
        float s = 0.f;
        for (int i = 0; i < 64; i += 4) {
            float4 a = *reinterpret_cast<const float4*>(&ctx[(size_t)row * 512 + l * 64 + i]);
            float4 v = *reinterpret_cast<const float4*>(&wc[l * 64 + i]);
            s += a.x * v.x + a.y * v.y + a.z * v.z + a.w * v.w;
        }
        s += __shfl_xor(s, 1); s += __shfl_xor(s, 2); s += __shfl_xor(s, 4);
        if (l == 0) cbuf[row] = s + c0[0];
    } else {
        int t = (b - 682) * 256 + tid;
        if (t < T_TOTAL) {
            int s = seg[t];
            if (t == 0) {
                for (int q = 0; q <= s; q++) starts[q] = 0;
            } else {
                int p = seg[t - 1];
                for (int q = p + 1; q <= s; q++) starts[q] = t;
            }
        }
    }
}

// ---------------------------------------------------------------------------
// zq_kernel: ZQ = context @ Wqz + bz  (fp32 [4096][256]); BM=32 tiles,
// grid (128,4) = 512 blocks = 2 blocks/CU.
// ---------------------------------------------------------------------------
__global__ __launch_bounds__(256) void zq_kernel(
    const float* __restrict__ ctx, const float* __restrict__ Wqz,
    const float* __restrict__ bz, float* __restrict__ zq) {
    __shared__ float As[2][16][44];
    const int tid = threadIdx.x;
    const int tm = tid & 7, tn = tid >> 3;
    const int row0 = blockIdx.x * 32, col0 = blockIdx.y * 64;
    const int lr = tid >> 3, lk = tid & 7;

    float acc[4][2];
#pragma unroll
    for (int i = 0; i < 4; i++) { acc[i][0] = 0.f; acc[i][1] = 0.f; }

    float2 av = *reinterpret_cast<const float2*>(&ctx[(size_t)(row0 + lr) * 512 + lk * 2]);
    for (int c = 0; c < 32; c++) {
        int cur = c & 1;
        As[cur][lk * 2 + 0][lr] = av.x;
        As[cur][lk * 2 + 1][lr] = av.y;
        __syncthreads();
        if (c < 31)
            av = *reinterpret_cast<const float2*>(
                &ctx[(size_t)(row0 + lr) * 512 + (c + 1) * 16 + lk * 2]);
#pragma unroll
        for (int k = 0; k < 16; k++) {
            float4 a = *reinterpret_cast<const float4*>(&As[cur][k][tm * 4]);
            float2 b = *reinterpret_cast<const float2*>(
                &Wqz[(size_t)(c * 16 + k) * 256 + col0 + tn * 2]);
            acc[0][0] += a.x * b.x; acc[0][1] += a.x * b.y;
            acc[1][0] += a.y * b.x; acc[1][1] += a.y * b.y;
            acc[2][0] += a.z * b.x; acc[2][1] += a.z * b.y;
            acc[3][0] += a.w * b.x; acc[3][1] += a.w * b.y;
        }
    }
    float2 bv = *reinterpret_cast<const float2*>(&bz[col0 + tn * 2]);
#pragma unroll
    for (int i = 0; i < 4; i++) {
        float2 o = {acc[i][0] + bv.x, acc[i][1] + bv.y};
        *reinterpret_cast<float2*>(
            &zq[(size_t)(row0 + tm * 4 + i) * 256 + col0 + tn * 2]) = o;
    }
}

// ---------------------------------------------------------------------------
// mlp_kernel: R6 structure (empirical best): M=128/block, 4 waves, wave =
// 128x64 output, acc[8][4] = 128 AGPR, (256,2). R10 change: ALL epilogues
// restructured ms-outer so part/sgm are per-iteration scalars (R6 held
// part[8]+segm[8]+temps live across the whole ns*ms loop -> ~50 regs of
// scratch spill, 100MB excess WRITE). Tripwire: WRITE > 150MB = still spills.
// Swizzle (all K): elem(m,k) at m*K + ((k>>3)^(m&15))*8 + (k&7).
// MFMA operand swap: D = W_frag x act_frag -> lane holds 4 consecutive n.
// ---------------------------------------------------------------------------
template <int K>
__device__ __forceinline__ void run_layer(
    const short* __restrict__ act, const short* __restrict__ Wt,
    int nbase, int l16, int quad, f32x4 acc[8][4]) {
    constexpr int KK = K / 32;
    const f32x4 zero = {0.f, 0.f, 0.f, 0.f};
#pragma unroll
    for (int i = 0; i < 8; i++)
#pragma unroll
        for (int j = 0; j < 4; j++) acc[i][j] = zero;

    int woff[4];
#pragma unroll
    for (int ns = 0; ns < 4; ns++)
        woff[ns] = ((nbase + ns * 16 + l16) * K + quad * 8) * 2;
    const int abase = l16 * K * 2;
    const char* actc = reinterpret_cast<const char*>(act);
    const char* wtc  = reinterpret_cast<const char*>(Wt);

    short8 wbuf[2][4];   // W double-buffered (L2 latency)
    short8 areg[8];      // A fragments for all 8 row-subtiles

#pragma unroll
    for (int ns = 0; ns < 4; ns++)
        wbuf[0][ns] = *reinterpret_cast<const short8*>(wtc + woff[ns]);

#pragma unroll
    for (int kk = 0; kk < KK; kk++) {
        if (kk + 1 < KK) {
#pragma unroll
            for (int ns = 0; ns < 4; ns++)
                wbuf[(kk + 1) & 1][ns] = *reinterpret_cast<const short8*>(
                    wtc + woff[ns] + (kk + 1) * 64);
        }
        {
            const int sg = (((kk * 4 + quad) ^ l16) * 16);
#pragma unroll
            for (int ms = 0; ms < 8; ms++)
                areg[ms] = *reinterpret_cast<const short8*>(
                    actc + abase + ms * 16 * K * 2 + sg);
        }
        const int cb = kk & 1;
#pragma unroll
        for (int ms = 0; ms < 8; ms++)
#pragma unroll
            for (int ns = 0; ns < 4; ns++)
                acc[ms][ns] = __builtin_amdgcn_mfma_f32_16x16x32_bf16(
                    wbuf[cb][ns], areg[ms], acc[ms][ns], 0, 0, 0);
    }
}

__global__ __launch_bounds__(256, 2) void mlp_kernel(
    const float* __restrict__ objects, const int* __restrict__ seg_ids,
    const short* __restrict__ W1T, const short* __restrict__ W2T,
    const short* __restrict__ W3vT,
    const float* __restrict__ b1, const float* __restrict__ b2,
    const float* __restrict__ b3,
    const float* __restrict__ zqbuf, const float* __restrict__ cbuf,
    float* __restrict__ logits_out, short* __restrict__ vout) {
    __shared__ __align__(16) short bufH[128 * 256];   // 64 KB: X -> h1 -> h2
    __shared__ float slots[4][128];

    const int tid  = threadIdx.x;
    const int wave = tid >> 6;
    const int lane = tid & 63;
    const int quad = lane >> 4;
    const int l16  = lane & 15;
    const int nbase = wave * 64;
    const int row0  = blockIdx.x * 128;

    // ---- stage X (fp32 -> bf16, K=128 swizzled layout in bufH[0:32KB])
    {
        const float4* op = reinterpret_cast<const float4*>(objects + (size_t)row0 * 128);
#pragma unroll
        for (int i = 0; i < 8; i++) {
            int u = tid + i * 256;           // 0..2047: m = u>>4, kg = u&15
            int m = u >> 4, kg = u & 15;
            float4 x0 = op[u * 2];
            float4 x1 = op[u * 2 + 1];
            short8 s;
            s[0] = f2bf(x0.x); s[1] = f2bf(x0.y); s[2] = f2bf(x0.z); s[3] = f2bf(x0.w);
            s[4] = f2bf(x1.x); s[5] = f2bf(x1.y); s[6] = f2bf(x1.z); s[7] = f2bf(x1.w);
            *reinterpret_cast<short8*>(&bufH[m * 128 + ((kg ^ (m & 15)) * 8)]) = s;
        }
    }
    __syncthreads();

    f32x4 acc[8][4];

    // ms-outer activation store: temps live only within one ms iteration
    auto store_act = [&](const float* __restrict__ bias) {
#pragma unroll
        for (int ms = 0; ms < 8; ms++) {
            int m = ms * 16 + l16;
#pragma unroll
            for (int ns = 0; ns < 4; ns++) {
                int n0 = nbase + ns * 16 + quad * 4;
                float4 bv = *reinterpret_cast<const float4*>(&bias[n0]);
                short4 s;
                s.x = f2bf(fmaxf(acc[ms][ns][0] + bv.x, 0.f));
                s.y = f2bf(fmaxf(acc[ms][ns][1] + bv.y, 0.f));
                s.z = f2bf(fmaxf(acc[ms][ns][2] + bv.z, 0.f));
                s.w = f2bf(fmaxf(acc[ms][ns][3] + bv.w, 0.f));
                *reinterpret_cast<short4*>(
                    &bufH[m * 256 + (((n0 >> 3) ^ (m & 15)) * 8) + (n0 & 7)]) = s;
            }
        }
    };

    // ---- layer 1: h1 = relu(X @ W1 + b1)
    run_layer<128>(bufH, W1T, nbase, l16, quad, acc);
    __syncthreads();                 // X fully consumed
    store_act(b1);
    __syncthreads();

    // ---- layer 2: h2 = relu(h1 @ W2 + b2); fold logits = h2.zq[seg]
    run_layer<256>(bufH, W2T, nbase, l16, quad, acc);
    __syncthreads();                 // h1 fully consumed
    {
#pragma unroll
        for (int ms = 0; ms < 8; ms++) {
            int m = ms * 16 + l16;
            int sgm = seg_ids[row0 + m];
            float part = 0.f;
#pragma unroll
            for (int ns = 0; ns < 4; ns++) {
                int n0 = nbase + ns * 16 + quad * 4;
                float4 bv = *reinterpret_cast<const float4*>(&b2[n0]);
                float h0 = fmaxf(acc[ms][ns][0] + bv.x, 0.f);
                float h1v = fmaxf(acc[ms][ns][1] + bv.y, 0.f);
                float h2v = fmaxf(acc[ms][ns][2] + bv.z, 0.f);
                float h3 = fmaxf(acc[ms][ns][3] + bv.w, 0.f);
                short4 s;
                s.x = f2bf(h0); s.y = f2bf(h1v); s.z = f2bf(h2v); s.w = f2bf(h3);
                *reinterpret_cast<short4*>(
                    &bufH[m * 256 + (((n0 >> 3) ^ (m & 15)) * 8) + (n0 & 7)]) = s;
                float4 zq4 = *reinterpret_cast<const float4*>(
                    &zqbuf[(size_t)sgm * 256 + n0]);
                part += h0 * zq4.x + h1v * zq4.y + h2v * zq4.z + h3 * zq4.w;
            }
            part += __shfl_xor(part, 16);
            part += __shfl_xor(part, 32);
            if (quad == 0) slots[wave][m] = part;
        }
    }
    __syncthreads();
    if (tid < 128) {
        int seg = seg_ids[row0 + tid];
        float s = slots[0][tid] + slots[1][tid] + slots[2][tid] + slots[3][tid] + cbuf[seg];
        logits_out[row0 + tid] = s * 0.0625f;   // / sqrt(256)
    }

    // ---- layer 3 v-half: v = h2 @ W3v + b3v; store direct from acc
    run_layer<256>(bufH, W3vT, nbase, l16, quad, acc);
#pragma unroll
    for (int ms = 0; ms < 8; ms++) {
        int m = ms * 16 + l16;
#pragma unroll
        for (int ns = 0; ns < 4; ns++) {
            int n0 = nbase + ns * 16 + quad * 4;
            float4 bv = *reinterpret_cast<const float4*>(&b3[256 + n0]);
            short4 s;
            s.x = f2bf(acc[ms][ns][0] + bv.x);
            s.y = f2bf(acc[ms][ns][1] + bv.y);
            s.z = f2bf(acc[ms][ns][2] + bv.z);
            s.w = f2bf(acc[ms][ns][3] + bv.w);
            *reinterpret_cast<short4*>(
                &vout[(size_t)(row0 + m) * 256 + n0]) = s;
        }
    }
}

// ---------------------------------------------------------------------------
// segment_kernel: per-segment softmax + weighted sum of v. One wave/segment.
// v-sum: short8/lane, 2 rows per wave-instruction, 4 pairs unrolled.
// ---------------------------------------------------------------------------
__global__ __launch_bounds__(64) void segment_kernel(
    const float* __restrict__ logits, const short* __restrict__ vbuf,
    const int* __restrict__ starts, float* __restrict__ emb,
    float* __restrict__ wout) {
    const int b = blockIdx.x;
    const int lane = threadIdx.x;
    const int start = starts[b];
    const int end = (b == B_SEG - 1) ? T_TOTAL : starts[b + 1];

    float mx = -1e30f;
    for (int t = start + lane; t < end; t += 64) mx = fmaxf(mx, logits[t]);
#pragma unroll
    for (int off = 32; off >= 1; off >>= 1) mx = fmaxf(mx, __shfl_xor(mx, off));

    float s = 0.f;
    for (int t = start + lane; t < end; t += 64) s += __expf(logits[t] - mx);
#pragma unroll
    for (int off = 32; off >= 1; off >>= 1) s += __shfl_xor(s, off);
    const float invz = 1.f / s;

    for (int t = start + lane; t < end; t += 64)
        wout[t] = __expf(logits[t] - mx) * invz;

    const int half = lane >> 5;
    const int c8 = (lane & 31) * 8;
    float a[4][8];
#pragma unroll
    for (int u = 0; u < 4; u++)
#pragma unroll
        for (int j = 0; j < 8; j++) a[u][j] = 0.f;

    int t = start;
    for (; t + 8 <= end; t += 8) {
#pragma unroll
        for (int u = 0; u < 4; u++) {
            int row = t + u * 2 + half;
            float wv = __expf(logits[row] - mx) * invz;
            short8 v8 = *reinterpret_cast<const short8*>(
                &vbuf[(size_t)row * 256 + c8]);
#pragma unroll
            for (int j = 0; j < 8; j++) a[u][j] += wv * bf2f(v8[j]);
        }
    }
    for (; t < end; t += 2) {
        int row = t + half;
        if (row < end) {
            float wv = __expf(logits[row] - mx) * invz;
            short8 v8 = *reinterpret_cast<const short8*>(
                &vbuf[(size_t)row * 256 + c8]);
#pragma unroll
            for (int j = 0; j < 8; j++) a[0][j] += wv * bf2f(v8[j]);
        }
    }
    float o[8];
#pragma unroll
    for (int j = 0; j < 8; j++) {
        o[j] = a[0][j] + a[1][j] + a[2][j] + a[3][j];
        o[j] += __shfl_xor(o[j], 32);
    }
    if (half == 0) {
        float4 o0 = {o[0], o[1], o[2], o[3]};
        float4 o1 = {o[4], o[5], o[6], o[7]};
        *reinterpret_cast<float4*>(&emb[(size_t)b * 256 + c8]) = o0;
        *reinterpret_cast<float4*>(&emb[(size_t)b * 256 + c8 + 4]) = o1;
    }
}

// ---------------------------------------------------------------------------
extern "C" void kernel_launch(void* const* d_in, const int* in_sizes, int n_in,
                              void* d_out, int out_size, void* d_ws, size_t ws_size,
                              hipStream_t stream) {
    const float* objects = (const float*)d_in[0];
    const float* context = (const float*)d_in[1];
    const int*   seg     = (const int*)d_in[2];
    const float* W1 = (const float*)d_in[3];
    const float* b1 = (const float*)d_in[4];
    const float* W2 = (const float*)d_in[5];
    const float* b2 = (const float*)d_in[6];
    const float* W3 = (const float*)d_in[7];
    const float* b3 = (const float*)d_in[8];
    const float* Wq = (const float*)d_in[9];
    const float* bq = (const float*)d_in[10];

    char* ws = (char*)d_ws;
    float* zqbuf = (float*)(ws);                        // 4 MB
    float* cbuf  = (float*)(ws + 4194304);              // 16 KB
    int*   seg_starts = (int*)(ws + 4227072);           // 16 KB
    short* W1T   = (short*)(ws + 4259840);              // 64 KB
    short* W2T   = (short*)(ws + 4325376);              // 128 KB
    short* W3vT  = (short*)(ws + 4456448);              // 128 KB
    // logits region (1 MB) doubles as scratch for Wqz/bz/wc/c0 (consumed
    // before mlp_kernel writes logits over it)
    char*  lreg   = ws + 4587520;
    float* logits = (float*)lreg;
    float* Wqz    = (float*)lreg;                       // 512 KB
    float* bz     = (float*)(lreg + 524288);            // 1 KB
    float* wc     = (float*)(lreg + 525312);            // 2 KB
    float* c0     = (float*)(lreg + 527360);            // 16 B
    short* vbuf   = (short*)(ws + 5636096);             // 128 MB

    float* emb  = (float*)d_out;
    float* wout = emb + (size_t)B_SEG * 256;

    prep_all<<<1706, 256, 0, stream>>>(W1, W2, W3, Wq, bq, b3, context, seg,
                                       W1T, W2T, W3vT, bz, wc, c0, Wqz, cbuf,
                                       seg_starts);
    zq_kernel<<<dim3(128, 4), 256, 0, stream>>>(context, Wqz, bz, zqbuf);
    mlp_kernel<<<T_TOTAL / 128, 256, 0, stream>>>(objects, seg, W1T, W2T, W3vT,
                                                  b1, b2, b3, zqbuf, cbuf,
                                                  logits, vbuf);
    segment_kernel<<<B_SEG, 64, 0, stream>>>(logits, vbuf, seg_starts, emb, wout);
}